// Round 2
// baseline (778.209 us; speedup 1.0000x reference)
//
#include <hip/hip_runtime.h>
#include <math.h>

#define NN 6000
#define EE 100000
#define ELL (EE + NN)   // edges + self loops for GAT
#define CAP 64          // bucket-CSR capacity per node (max deg ~45 << 64)
#define NBLK 512        // 2 blocks/CU * 256 CUs; co-resident by __launch_bounds__(256,2)

// packed CSR entry: src (13b) | rel<<13 | self<<14
#define PK_SRC(p)  ((p) & 0x1FFF)
#define PK_REL(p)  (((p) >> 13) & 1)
#define PK_SELF(p) ((p) & 0x4000)

typedef __attribute__((ext_vector_type(8))) short frag8;           // 8 bf16 (4 VGPR)
typedef __attribute__((ext_vector_type(4))) float f32x4;
typedef __attribute__((ext_vector_type(8))) unsigned short u16x8;  // 16B of bf16

__device__ __forceinline__ unsigned short f2bf(float f){
  unsigned u = __float_as_uint(f);
  unsigned r = u + 0x7FFFu + ((u >> 16) & 1u);   // round-to-nearest-even
  return (unsigned short)(r >> 16);
}
__device__ __forceinline__ float bf2f(unsigned short s){
  return __uint_as_float(((unsigned)s) << 16);
}

// Software grid barrier (sense-reversal via phase counter).
// Safe across XCDs: agent-scope atomics at the coherence point + __threadfence
// (release: L2 writeback; acquire: L2 invalidate). Bounded spin: a logic bug
// degrades to wrong results + counters, never a hung container.
__device__ __forceinline__ void gbar(unsigned* cnt, unsigned* phs){
  __syncthreads();                      // all block stores drained to this XCD's L2
  if (threadIdx.x == 0){
    __threadfence();                    // writeback L2 -> LLC (release)
    unsigned ph  = __hip_atomic_load(phs, __ATOMIC_RELAXED, __HIP_MEMORY_SCOPE_AGENT);
    unsigned arr = __hip_atomic_fetch_add(cnt, 1u, __ATOMIC_ACQ_REL, __HIP_MEMORY_SCOPE_AGENT);
    if (arr == (unsigned)(NBLK - 1)){
      __hip_atomic_store(cnt, 0u, __ATOMIC_RELAXED, __HIP_MEMORY_SCOPE_AGENT);
      __hip_atomic_fetch_add(phs, 1u, __ATOMIC_ACQ_REL, __HIP_MEMORY_SCOPE_AGENT);
    } else {
      int spins = 0;
      while (__hip_atomic_load(phs, __ATOMIC_RELAXED, __HIP_MEMORY_SCOPE_AGENT) == ph){
        __builtin_amdgcn_s_sleep(8);    // ~512 clk between polls
        if (++spins > (1 << 20)) break; // escape hatch: wrong answer, not a hang
      }
    }
    __threadfence();                    // invalidate L2 (acquire) before next stage reads
  }
  __syncthreads();
}

struct FArgs {
  const int* ei; const int* et;
  unsigned* bar;                 // [0]=count, [1]=phase
  int* cursor; int* pks;
  const float* basis0; const float* comp0; const float* root0; const float* rbias0;
  const float* basis1; const float* comp1; const float* root1; const float* rbias1;
  const float* basis2; const float* comp2; const float* root2; const float* rbias2;
  const float* basis3; const float* comp3; const float* root3; const float* rbias3;
  const float* gat_w; const float* a_src; const float* a_dst; const float* gat_b;
  const float* w1; const float* b1m; const float* w2; const float* b2m;
  unsigned short* W016; float* Wcat; unsigned short* Bt16;
  unsigned short* H16a; unsigned short* H16b;
  unsigned short* h16; float* asv; float* adv;
  unsigned short* gout16; unsigned short* P16;
  float* out;
};

// One regular (non-cooperative) kernel for the whole pipeline.
// Stage boundaries = gbar() (replaces 8 kernel-launch drains).
// Ragged gathers use register-staged CSR rows + __shfl broadcast so payload
// loads are independent (no pks[j] -> load dependency chain).
__global__ void __launch_bounds__(256, 2) k_fused(FArgs A){
  __shared__ float sx[8*64];
  __shared__ float red[4][16];
  const int t    = threadIdx.x;
  const int gsz  = NBLK * 256;
  const int gtid = (int)blockIdx.x * 256 + t;
  unsigned* bcnt = A.bar;
  unsigned* bphs = A.bar + 1;

  // ---- S1: bucket-CSR fill + W0 bf16 + Wcat + w1->Bt16 ----
  // (cursor zeroed by hipMemsetAsync before launch)
  for (int t0 = gtid; t0 < 2*NN*32 + 24576 + 256*512; t0 += gsz){
    if (t0 < ELL){
      int d, pk;
      if (t0 < EE){ d = A.ei[EE+t0]; pk = A.ei[t0] | (A.et[t0] << 13); }
      else        { d = t0 - EE; pk = d | 0x4000; }
      int pos = atomicAdd(&A.cursor[d], 1);
      A.pks[d*CAP + pos] = pk;
    }
    if (t0 < 2*NN*32){
      int r = t0 / (NN*32);
      int no = t0 - r*(NN*32);
      float acc = 0.f;
      #pragma unroll
      for (int b=0;b<4;b++) acc += A.comp0[r*4+b] * A.basis0[b*(NN*32)+no];
      A.W016[t0] = f2bf(acc);
    } else {
      int tw = t0 - 2*NN*32;
      if (tw < 24576){
        const float *bb,*cc,*rr; int I,O; int tt = tw;
        if (tw < 6144)        { bb=A.basis1;cc=A.comp1;rr=A.root1;I=32;O=64; }
        else if (tw < 18432)  { bb=A.basis2;cc=A.comp2;rr=A.root2;I=64;O=64; tt -= 6144; }
        else                  { bb=A.basis3;cc=A.comp3;rr=A.root3;I=64;O=32; tt -= 18432; }
        int C = 3*O;
        int i = tt / C; int col = tt - i*C;
        float v;
        if (col < O) v = rr[i*O + col];
        else {
          int r = (col - O) / O; int o = col - O - r*O;
          v = 0.f;
          #pragma unroll
          for (int b=0;b<4;b++) v += cc[r*4+b]*bb[(b*I+i)*O + o];
        }
        A.Wcat[tw] = v;
      } else {
        int tb = tw - 24576;           // Bt16: [n][k], n in [0,256), k in [0,512)
        int n = tb >> 9, k = tb & 511;
        float v = (n < 128) ? A.w1[k*128 + n] : A.w1[(512+k)*128 + (n-128)];
        A.Bt16[tb] = f2bf(v);
      }
    }
  }
  gbar(bcnt, bphs);

  // ---- S2: layer-0 gather (x=I) + layer-1 nodemm -> H16a [N,192] ----
  for (int g = blockIdx.x; g < NN/8; g += NBLK){
    int nl = t>>5, o = t&31, n = g*8 + nl;
    int r0 = n*CAP, deg = A.cursor[n];
    int pk0 = (o      < deg) ? A.pks[r0 + o]      : 0x4000;   // self => skipped
    int pk1 = (32 + o < deg) ? A.pks[r0 + 32 + o] : 0x4000;
    float a0=0.f, a1=0.f, c0=0.f, c1=0.f;
    int d0 = min(deg,32), d1 = deg - d0;
    for (int j=0;j<d0;j++){
      int p = __shfl(pk0, j, 32);
      if (!PK_SELF(p)){
        float v = bf2f(A.W016[(PK_REL(p)*NN + PK_SRC(p))*32 + o]);
        if (PK_REL(p)==0){ a0 += v; c0 += 1.f; } else { a1 += v; c1 += 1.f; }
      }
    }
    for (int j=0;j<d1;j++){
      int p = __shfl(pk1, j, 32);
      if (!PK_SELF(p)){
        float v = bf2f(A.W016[(PK_REL(p)*NN + PK_SRC(p))*32 + o]);
        if (PK_REL(p)==0){ a0 += v; c0 += 1.f; } else { a1 += v; c1 += 1.f; }
      }
    }
    sx[nl*32+o] = tanhf(A.root0[n*32+o] + A.rbias0[o]
                        + a0/fmaxf(c0,1.f) + a1/fmaxf(c1,1.f));
    __syncthreads();
    if (t < 192){
      float acc[8] = {0,0,0,0,0,0,0,0};
      for (int i=0;i<32;i++){
        float w = A.Wcat[i*192 + t];
        #pragma unroll
        for (int tt=0;tt<8;tt++) acc[tt] += sx[tt*32+i]*w;
      }
      #pragma unroll
      for (int tt=0;tt<8;tt++) A.H16a[(g*8+tt)*192 + t] = f2bf(acc[tt]);
    }
    __syncthreads();
  }
  gbar(bcnt, bphs);

  // ---- S3: ragg<64> on H16a + nodemm 64x192 -> H16b ----
  for (int g = blockIdx.x; g < NN/8; g += NBLK){
    int nl = t>>5, og = t&31, o0 = og*2, n = g*8 + nl;
    int r0 = n*CAP, deg = A.cursor[n];
    int pk0 = (og      < deg) ? A.pks[r0 + og]      : 0x4000;
    int pk1 = (32 + og < deg) ? A.pks[r0 + 32 + og] : 0x4000;
    float a00=0.f, a01=0.f, a10=0.f, a11=0.f, c0=0.f, c1=0.f;
    int d0 = min(deg,32), d1 = deg - d0;
    for (int j=0;j<d0;j++){
      int p = __shfl(pk0, j, 32);
      if (!PK_SELF(p)){
        int rel = PK_REL(p);
        unsigned hv = *(const unsigned*)&A.H16a[PK_SRC(p)*192 + 64 + rel*64 + o0];
        float v0 = bf2f((unsigned short)(hv & 0xFFFF));
        float v1 = bf2f((unsigned short)(hv >> 16));
        if (rel==0){ a00 += v0; a01 += v1; c0 += 1.f; } else { a10 += v0; a11 += v1; c1 += 1.f; }
      }
    }
    for (int j=0;j<d1;j++){
      int p = __shfl(pk1, j, 32);
      if (!PK_SELF(p)){
        int rel = PK_REL(p);
        unsigned hv = *(const unsigned*)&A.H16a[PK_SRC(p)*192 + 64 + rel*64 + o0];
        float v0 = bf2f((unsigned short)(hv & 0xFFFF));
        float v1 = bf2f((unsigned short)(hv >> 16));
        if (rel==0){ a00 += v0; a01 += v1; c0 += 1.f; } else { a10 += v0; a11 += v1; c1 += 1.f; }
      }
    }
    float i0 = 1.f/fmaxf(c0,1.f), i1 = 1.f/fmaxf(c1,1.f);
    sx[nl*64+o0]   = tanhf(bf2f(A.H16a[n*192+o0])   + A.rbias1[o0]   + a00*i0 + a10*i1);
    sx[nl*64+o0+1] = tanhf(bf2f(A.H16a[n*192+o0+1]) + A.rbias1[o0+1] + a01*i0 + a11*i1);
    __syncthreads();
    if (t < 192){
      const float* Wc = A.Wcat + 6144;
      float acc[8] = {0,0,0,0,0,0,0,0};
      for (int i=0;i<64;i++){
        float w = Wc[i*192 + t];
        #pragma unroll
        for (int tt=0;tt<8;tt++) acc[tt] += sx[tt*64+i]*w;
      }
      #pragma unroll
      for (int tt=0;tt<8;tt++) A.H16b[(g*8+tt)*192 + t] = f2bf(acc[tt]);
    }
    __syncthreads();
  }
  gbar(bcnt, bphs);

  // ---- S4: ragg<64> on H16b + nodemm 64x96 -> H16a [N,96] ----
  for (int g = blockIdx.x; g < NN/8; g += NBLK){
    int nl = t>>5, og = t&31, o0 = og*2, n = g*8 + nl;
    int r0 = n*CAP, deg = A.cursor[n];
    int pk0 = (og      < deg) ? A.pks[r0 + og]      : 0x4000;
    int pk1 = (32 + og < deg) ? A.pks[r0 + 32 + og] : 0x4000;
    float a00=0.f, a01=0.f, a10=0.f, a11=0.f, c0=0.f, c1=0.f;
    int d0 = min(deg,32), d1 = deg - d0;
    for (int j=0;j<d0;j++){
      int p = __shfl(pk0, j, 32);
      if (!PK_SELF(p)){
        int rel = PK_REL(p);
        unsigned hv = *(const unsigned*)&A.H16b[PK_SRC(p)*192 + 64 + rel*64 + o0];
        float v0 = bf2f((unsigned short)(hv & 0xFFFF));
        float v1 = bf2f((unsigned short)(hv >> 16));
        if (rel==0){ a00 += v0; a01 += v1; c0 += 1.f; } else { a10 += v0; a11 += v1; c1 += 1.f; }
      }
    }
    for (int j=0;j<d1;j++){
      int p = __shfl(pk1, j, 32);
      if (!PK_SELF(p)){
        int rel = PK_REL(p);
        unsigned hv = *(const unsigned*)&A.H16b[PK_SRC(p)*192 + 64 + rel*64 + o0];
        float v0 = bf2f((unsigned short)(hv & 0xFFFF));
        float v1 = bf2f((unsigned short)(hv >> 16));
        if (rel==0){ a00 += v0; a01 += v1; c0 += 1.f; } else { a10 += v0; a11 += v1; c1 += 1.f; }
      }
    }
    float i0 = 1.f/fmaxf(c0,1.f), i1 = 1.f/fmaxf(c1,1.f);
    sx[nl*64+o0]   = tanhf(bf2f(A.H16b[n*192+o0])   + A.rbias2[o0]   + a00*i0 + a10*i1);
    sx[nl*64+o0+1] = tanhf(bf2f(A.H16b[n*192+o0+1]) + A.rbias2[o0+1] + a01*i0 + a11*i1);
    __syncthreads();
    if (t < 192){
      const float* Wc = A.Wcat + 18432;
      int c = t % 96, grp = t / 96;            // grp 0/1: nodes grp*4..+3
      float acc[4] = {0,0,0,0};
      for (int i=0;i<64;i++){
        float w = Wc[i*96 + c];
        #pragma unroll
        for (int tt=0;tt<4;tt++) acc[tt] += sx[(grp*4+tt)*64+i]*w;
      }
      #pragma unroll
      for (int tt=0;tt<4;tt++) A.H16a[(g*8+grp*4+tt)*96 + c] = f2bf(acc[tt]);
    }
    __syncthreads();
  }
  gbar(bcnt, bphs);

  // ---- S5: ragg<32> on H16a(stride 96) + GAT h=x@gw + scores ----
  for (int g = blockIdx.x; g < NN/8; g += NBLK){
    int nl = t>>5, o = t&31, n = g*8 + nl;
    int r0 = n*CAP, deg = A.cursor[n];
    int pk0 = (o      < deg) ? A.pks[r0 + o]      : 0x4000;
    int pk1 = (32 + o < deg) ? A.pks[r0 + 32 + o] : 0x4000;
    float a0=0.f, a1=0.f, c0=0.f, c1=0.f;
    int d0 = min(deg,32), d1 = deg - d0;
    for (int j=0;j<d0;j++){
      int p = __shfl(pk0, j, 32);
      if (!PK_SELF(p)){
        int rel = PK_REL(p);
        float v = bf2f(A.H16a[PK_SRC(p)*96 + 32 + rel*32 + o]);
        if (rel==0){ a0 += v; c0 += 1.f; } else { a1 += v; c1 += 1.f; }
      }
    }
    for (int j=0;j<d1;j++){
      int p = __shfl(pk1, j, 32);
      if (!PK_SELF(p)){
        int rel = PK_REL(p);
        float v = bf2f(A.H16a[PK_SRC(p)*96 + 32 + rel*32 + o]);
        if (rel==0){ a0 += v; c0 += 1.f; } else { a1 += v; c1 += 1.f; }
      }
    }
    sx[nl*32+o] = tanhf(bf2f(A.H16a[n*96+o]) + A.rbias3[o]
                        + a0/fmaxf(c0,1.f) + a1/fmaxf(c1,1.f));
    __syncthreads();
    int c2 = t*2;
    float2 acc[8];
    #pragma unroll
    for (int k=0;k<8;k++) acc[k] = {0.f,0.f};
    for (int i=0;i<32;i++){
      const float2 gv = *(const float2*)&A.gat_w[i*512 + c2];
      #pragma unroll
      for (int k=0;k<8;k++){
        float xv = sx[k*32+i];
        acc[k].x += xv*gv.x; acc[k].y += xv*gv.y;
      }
    }
    const float2 a2 = *(const float2*)&A.a_src[c2];
    const float2 d2 = *(const float2*)&A.a_dst[c2];
    float sa[8], sd[8];
    #pragma unroll
    for (int k=0;k<8;k++){
      ushort2 ov;
      ov.x = f2bf(acc[k].x); ov.y = f2bf(acc[k].y);
      *(ushort2*)&A.h16[(size_t)(g*8+k)*512 + c2] = ov;
      sa[k] = acc[k].x*a2.x + acc[k].y*a2.y;
      sd[k] = acc[k].x*d2.x + acc[k].y*d2.y;
    }
    #pragma unroll
    for (int m=32;m>0;m>>=1){
      #pragma unroll
      for (int k=0;k<8;k++){ sa[k] += __shfl_xor(sa[k],m,64); sd[k] += __shfl_xor(sd[k],m,64); }
    }
    int wvv = t>>6;
    if ((t&63)==0){
      #pragma unroll
      for (int k=0;k<8;k++){ red[wvv][k]=sa[k]; red[wvv][8+k]=sd[k]; }
    }
    __syncthreads();
    if (t<8)        A.asv[g*8+t]   = red[0][t]+red[1][t]+red[2][t]+red[3][t];
    else if (t<16)  A.adv[g*8+t-8] = red[0][t]+red[1][t]+red[2][t]+red[3][t];
    __syncthreads();
  }
  gbar(bcnt, bphs);

  // ---- S6: GAT softmax+aggregate, 1 wave per node, shuffle-only ----
  {
    int wv = t>>6, lane = t&63;
    for (int n = (int)blockIdx.x*4 + wv; n < NN; n += NBLK*4){
      int r0 = n*CAP, deg = A.cursor[n];           // deg <= CAP = 64: one chunk
      float advn = A.adv[n];
      int pk  = (lane < deg) ? A.pks[r0 + lane] : -1;
      int src = (pk >= 0) ? PK_SRC(pk) : 0;
      float aa = -1e30f;
      if (pk >= 0){
        float a = A.asv[src] + advn;
        aa = (a >= 0.f) ? a : 0.2f*a;
      }
      float m = aa;
      #pragma unroll
      for (int off=32;off>0;off>>=1) m = fmaxf(m, __shfl_xor(m,off,64));
      float ex = (pk >= 0) ? expf(aa - m) : 0.f;
      float sumex = ex;
      #pragma unroll
      for (int off=32;off>0;off>>=1) sumex += __shfl_xor(sumex,off,64);
      float acc[8] = {0,0,0,0,0,0,0,0};
      for (int e=0;e<deg;e++){
        float cf = __shfl(ex, e, 64);
        int s    = __shfl(src, e, 64);
        const u16x8 hv = *(const u16x8*)&A.h16[(size_t)s*512 + lane*8];
        #pragma unroll
        for (int q=0;q<8;q++) acc[q] += cf * bf2f(hv[q]);
      }
      float inv = 1.f / fmaxf(sumex, 1e-16f);
      const float4 b0  = *(const float4*)&A.gat_b[lane*8];
      const float4 b1v = *(const float4*)&A.gat_b[lane*8+4];
      u16x8 o;
      o[0] = f2bf(fmaxf(acc[0]*inv + b0.x, 0.f));
      o[1] = f2bf(fmaxf(acc[1]*inv + b0.y, 0.f));
      o[2] = f2bf(fmaxf(acc[2]*inv + b0.z, 0.f));
      o[3] = f2bf(fmaxf(acc[3]*inv + b0.w, 0.f));
      o[4] = f2bf(fmaxf(acc[4]*inv + b1v.x, 0.f));
      o[5] = f2bf(fmaxf(acc[5]*inv + b1v.y, 0.f));
      o[6] = f2bf(fmaxf(acc[6]*inv + b1v.z, 0.f));
      o[7] = f2bf(fmaxf(acc[7]*inv + b1v.w, 0.f));
      *(u16x8*)&A.gout16[(size_t)n*512 + lane*8] = o;
    }
  }
  gbar(bcnt, bphs);

  // ---- S7: P16[6000][256] = gout16 @ Bt16^T via MFMA ----
  {
    int wv = t>>6, lane = t&63;
    for (int tile = (int)blockIdx.x*4 + wv; tile < 1500; tile += NBLK*4){
      int mt = tile >> 2;
      int nt = tile & 3;
      int kq = (lane >> 4) * 8;
      const unsigned short* arow  = A.gout16 + (size_t)(mt*16 + (lane & 15))*512 + kq;
      const unsigned short* bbase = A.Bt16   + (size_t)(nt*64 + (lane & 15))*512 + kq;
      f32x4 acc0 = {0,0,0,0}, acc1 = {0,0,0,0}, acc2 = {0,0,0,0}, acc3 = {0,0,0,0};
      for (int k = 0; k < 512; k += 32){
        frag8 a  = *(const frag8*)(arow + k);
        frag8 b0 = *(const frag8*)(bbase + k);
        frag8 b1 = *(const frag8*)(bbase + 16*512 + k);
        frag8 b2 = *(const frag8*)(bbase + 32*512 + k);
        frag8 b3 = *(const frag8*)(bbase + 48*512 + k);
        acc0 = __builtin_amdgcn_mfma_f32_16x16x32_bf16(a, b0, acc0, 0, 0, 0);
        acc1 = __builtin_amdgcn_mfma_f32_16x16x32_bf16(a, b1, acc1, 0, 0, 0);
        acc2 = __builtin_amdgcn_mfma_f32_16x16x32_bf16(a, b2, acc2, 0, 0, 0);
        acc3 = __builtin_amdgcn_mfma_f32_16x16x32_bf16(a, b3, acc3, 0, 0, 0);
      }
      int rowb = mt*16 + (lane >> 4)*4;
      int col  = nt*64 + (lane & 15);
      #pragma unroll
      for (int i=0;i<4;i++){
        A.P16[(size_t)(rowb+i)*256 + col     ] = f2bf(acc0[i]);
        A.P16[(size_t)(rowb+i)*256 + col + 16] = f2bf(acc1[i]);
        A.P16[(size_t)(rowb+i)*256 + col + 32] = f2bf(acc2[i]);
        A.P16[(size_t)(rowb+i)*256 + col + 48] = f2bf(acc3[i]);
      }
    }
  }
  gbar(bcnt, bphs);

  // ---- S8: per-edge MLP head, 16 lanes/edge ----
  {
    int l = t & 15;
    for (int e = (int)blockIdx.x*16 + (t>>4); e < EE; e += NBLK*16){
      int s = A.ei[e], d = A.ei[EE+e];
      const u16x8 Av = *(const u16x8*)&A.P16[(size_t)s*256 + l*8];
      const u16x8 Bv = *(const u16x8*)&A.P16[(size_t)d*256 + 128 + l*8];
      const float4 b1a = *(const float4*)&A.b1m[l*8];
      const float4 b1b = *(const float4*)&A.b1m[l*8+4];
      const float4 w2a = *(const float4*)&A.w2[l*8];
      const float4 w2b = *(const float4*)&A.w2[l*8+4];
      float h0 = fmaxf(bf2f(Av[0])+bf2f(Bv[0])+b1a.x, 0.f);
      float h1 = fmaxf(bf2f(Av[1])+bf2f(Bv[1])+b1a.y, 0.f);
      float h2 = fmaxf(bf2f(Av[2])+bf2f(Bv[2])+b1a.z, 0.f);
      float h3 = fmaxf(bf2f(Av[3])+bf2f(Bv[3])+b1a.w, 0.f);
      float h4 = fmaxf(bf2f(Av[4])+bf2f(Bv[4])+b1b.x, 0.f);
      float h5 = fmaxf(bf2f(Av[5])+bf2f(Bv[5])+b1b.y, 0.f);
      float h6 = fmaxf(bf2f(Av[6])+bf2f(Bv[6])+b1b.z, 0.f);
      float h7 = fmaxf(bf2f(Av[7])+bf2f(Bv[7])+b1b.w, 0.f);
      float acc = h0*w2a.x + h1*w2a.y + h2*w2a.z + h3*w2a.w
                + h4*w2b.x + h5*w2b.y + h6*w2b.z + h7*w2b.w;
      #pragma unroll
      for (int m=8;m>0;m>>=1) acc += __shfl_xor(acc,m,64);
      if (l==0) A.out[e] = 1.f/(1.f + expf(-(acc + A.b2m[0])));
    }
  }
}

extern "C" void kernel_launch(void* const* d_in, const int* in_sizes, int n_in,
                              void* d_out, int out_size, void* d_ws, size_t ws_size,
                              hipStream_t stream){
  FArgs A;
  A.basis0 = (const float*)d_in[0];
  A.comp0  = (const float*)d_in[1];
  A.root0  = (const float*)d_in[2];
  A.rbias0 = (const float*)d_in[3];
  A.basis1 = (const float*)d_in[4];
  A.comp1  = (const float*)d_in[5];
  A.root1  = (const float*)d_in[6];
  A.rbias1 = (const float*)d_in[7];
  A.basis2 = (const float*)d_in[8];
  A.comp2  = (const float*)d_in[9];
  A.root2  = (const float*)d_in[10];
  A.rbias2 = (const float*)d_in[11];
  A.basis3 = (const float*)d_in[12];
  A.comp3  = (const float*)d_in[13];
  A.root3  = (const float*)d_in[14];
  A.rbias3 = (const float*)d_in[15];
  A.gat_w  = (const float*)d_in[16];
  A.a_src  = (const float*)d_in[17];
  A.a_dst  = (const float*)d_in[18];
  A.gat_b  = (const float*)d_in[19];
  A.w1     = (const float*)d_in[20];
  A.b1m    = (const float*)d_in[21];
  A.w2     = (const float*)d_in[22];
  A.b2m    = (const float*)d_in[23];
  A.ei     = (const int*)d_in[24];
  A.et     = (const int*)d_in[25];
  A.out    = (float*)d_out;

  // workspace carve-up (16B-aligned sections)
  float* p = (float*)d_ws;
  A.bar    = (unsigned*)p; p += 4;           // [0]=count, [1]=phase (+pad)
  A.cursor = (int*)p; p += NN;               // doubles as degree after S1
  A.pks    = (int*)p; p += NN*CAP;           // bucket CSR (64 slots/node)
  A.W016 = (unsigned short*)p; p += NN*32;   // 2*NN*32 bf16
  A.Wcat = p; p += 24576;
  A.Bt16 = (unsigned short*)p; p += 256*512/2;
  A.H16a = (unsigned short*)p; p += NN*96;   // NN*192 bf16
  A.H16b = (unsigned short*)p; p += NN*96;   // NN*192 bf16
  A.h16  = (unsigned short*)p; p += NN*256;  // NN*512 bf16
  A.asv  = p; p += NN;
  A.adv  = p; p += NN;
  A.gout16 = (unsigned short*)p; p += NN*256; // NN*512 bf16
  A.P16  = (unsigned short*)p; p += NN*128;   // NN*256 bf16

  // zero barrier state + cursors in one small in-stream memset (capture-safe)
  hipMemsetAsync(A.bar, 0, (size_t)(4 + NN)*sizeof(int), stream);
  k_fused<<<dim3(NBLK), dim3(256), 0, stream>>>(A);
}

// Round 3
// 216.482 us; speedup vs baseline: 3.5948x; 3.5948x over previous
//
#include <hip/hip_runtime.h>
#include <math.h>

#define NN 6000
#define EE 100000
#define ELL (EE + NN)   // edges + self loops for GAT
#define CAP 64          // bucket-CSR capacity per node (max deg ~45 << 64)

// packed CSR entry: src (13b) | rel<<13 | self<<14
#define PK_SRC(p)  ((p) & 0x1FFF)
#define PK_REL(p)  (((p) >> 13) & 1)
#define PK_SELF(p) ((p) & 0x4000)

typedef __attribute__((ext_vector_type(8))) short frag8;           // 8 bf16 (4 VGPR)
typedef __attribute__((ext_vector_type(4))) float f32x4;
typedef __attribute__((ext_vector_type(8))) unsigned short u16x8;  // 16B of bf16

__device__ __forceinline__ unsigned short f2bf(float f){
  unsigned u = __float_as_uint(f);
  unsigned r = u + 0x7FFFu + ((u >> 16) & 1u);   // round-to-nearest-even
  return (unsigned short)(r >> 16);
}
__device__ __forceinline__ float bf2f(unsigned short s){
  return __uint_as_float(((unsigned)s) << 16);
}

// ---- fused: bucket-CSR fill + weight prep (W0 bf16) + w1->Bt bf16 ----
// cursor[] doubles as the per-node degree after this kernel completes.
__global__ void k_pdc(const int* __restrict__ ei, const int* __restrict__ et,
                      int* __restrict__ cursor, int* __restrict__ pks,
                      const float* __restrict__ basis0, const float* __restrict__ comp0,
                      const float* __restrict__ b1,const float* __restrict__ c1,const float* __restrict__ r1,
                      const float* __restrict__ b2,const float* __restrict__ c2,const float* __restrict__ r2,
                      const float* __restrict__ b3,const float* __restrict__ c3,const float* __restrict__ r3,
                      const float* __restrict__ w1,
                      unsigned short* __restrict__ W016, float* __restrict__ Wcat,
                      unsigned short* __restrict__ Bt16){
  int t0 = blockIdx.x*256 + threadIdx.x;
  if (t0 < ELL){
    int d, pk;
    if (t0 < EE){
      d = ei[EE+t0];
      pk = ei[t0] | (et[t0] << 13);
    } else {
      d = t0 - EE; pk = d | 0x4000;
    }
    int pos = atomicAdd(&cursor[d], 1);
    pks[d*CAP + pos] = pk;
  }
  if (t0 < 2*NN*32){
    int r = t0 / (NN*32);
    int no = t0 - r*(NN*32);
    float acc = 0.f;
    #pragma unroll
    for (int b=0;b<4;b++) acc += comp0[r*4+b] * basis0[b*(NN*32)+no];
    W016[t0] = f2bf(acc);
    return;
  }
  int tw = t0 - 2*NN*32;
  if (tw < 24576){
    const float *bb,*cc,*rr; int I,O; int t = tw;
    if (tw < 6144)        { bb=b1;cc=c1;rr=r1;I=32;O=64; }
    else if (tw < 18432)  { bb=b2;cc=c2;rr=r2;I=64;O=64; t -= 6144; }
    else                  { bb=b3;cc=c3;rr=r3;I=64;O=32; t -= 18432; }
    int C = 3*O;
    int i = t / C; int col = t - i*C;
    float v;
    if (col < O) v = rr[i*O + col];
    else {
      int r = (col - O) / O; int o = col - O - r*O;
      v = 0.f;
      #pragma unroll
      for (int b=0;b<4;b++) v += cc[r*4+b]*bb[(b*I+i)*O + o];
    }
    Wcat[tw] = v;
    return;
  }
  int tb = tw - 24576;           // Bt16: [n][k], n in [0,256), k in [0,512)
  if (tb >= 256*512) return;
  int n = tb >> 9, k = tb & 511;
  float v = (n < 128) ? w1[k*128 + n] : w1[(512+k)*128 + (n-128)];
  Bt16[tb] = f2bf(v);
}

// ---- F1: layer-0 gather (x=I) + layer-1 nodemm -> H16 [N,192] ----
// Gather uses register-staged CSR row + __shfl broadcast: pk values live in
// registers so every payload load address is computable immediately -> deep
// load pipelining (no pks[j] -> load dependency chain).
__global__ void __launch_bounds__(256) k_f1(
    const unsigned short* __restrict__ W016, const float* __restrict__ root,
    const float* __restrict__ rbias0,
    const int* __restrict__ degc, const int* __restrict__ pks,
    const float* __restrict__ Wc, unsigned short* __restrict__ Hout){
  __shared__ float sx[8*32];
  int n0 = blockIdx.x*8;
  int t = threadIdx.x, nl = t>>5, o = t&31, n = n0+nl;
  int r0 = n*CAP, deg = degc[n];
  int pk0 = (o      < deg) ? pks[r0 + o]      : 0x4000;   // self => skipped
  int pk1 = (32 + o < deg) ? pks[r0 + 32 + o] : 0x4000;
  float a0 = 0.f, a1 = 0.f, c0 = 0.f, c1 = 0.f;
  int d0 = min(deg,32), d1 = deg - d0;
  for (int j=0;j<d0;j++){
    int p = __shfl(pk0, j, 32);
    if (!PK_SELF(p)){
      float v = bf2f(W016[(PK_REL(p)*NN + PK_SRC(p))*32 + o]);
      if (PK_REL(p)==0){ a0 += v; c0 += 1.f; } else { a1 += v; c1 += 1.f; }
    }
  }
  for (int j=0;j<d1;j++){
    int p = __shfl(pk1, j, 32);
    if (!PK_SELF(p)){
      float v = bf2f(W016[(PK_REL(p)*NN + PK_SRC(p))*32 + o]);
      if (PK_REL(p)==0){ a0 += v; c0 += 1.f; } else { a1 += v; c1 += 1.f; }
    }
  }
  sx[nl*32+o] = tanhf(root[n*32+o] + rbias0[o]
                      + a0/fmaxf(c0,1.f) + a1/fmaxf(c1,1.f));
  __syncthreads();
  if (t < 192){
    float acc[8] = {0,0,0,0,0,0,0,0};
    for (int i=0;i<32;i++){
      float w = Wc[i*192 + t];
      #pragma unroll
      for (int tt=0;tt<8;tt++) acc[tt] += sx[tt*32+i]*w;
    }
    #pragma unroll
    for (int tt=0;tt<8;tt++) Hout[(n0+tt)*192 + t] = f2bf(acc[tt]);
  }
}

// ---- F2: ragg<64> (Hin stride 192) + nodemm 64x192 -> Hout [N,192] ----
__global__ void __launch_bounds__(256) k_f2(
    const unsigned short* __restrict__ Hin, const float* __restrict__ rbias,
    const int* __restrict__ degc, const int* __restrict__ pks,
    const float* __restrict__ Wc, unsigned short* __restrict__ Hout){
  __shared__ float sx[8*64];
  int n0 = blockIdx.x*8;
  int t = threadIdx.x, nl = t>>5, og = t&31, o0 = og*2, n = n0+nl;
  int r0 = n*CAP, deg = degc[n];
  int pk0 = (og      < deg) ? pks[r0 + og]      : 0x4000;
  int pk1 = (32 + og < deg) ? pks[r0 + 32 + og] : 0x4000;
  float a00=0.f, a01=0.f, a10=0.f, a11=0.f, c0=0.f, c1=0.f;
  int d0 = min(deg,32), d1 = deg - d0;
  for (int j=0;j<d0;j++){
    int p = __shfl(pk0, j, 32);
    if (!PK_SELF(p)){
      int rel = PK_REL(p);
      unsigned hv = *(const unsigned*)&Hin[PK_SRC(p)*192 + 64 + rel*64 + o0];
      float v0 = bf2f((unsigned short)(hv & 0xFFFF));
      float v1 = bf2f((unsigned short)(hv >> 16));
      if (rel==0){ a00 += v0; a01 += v1; c0 += 1.f; } else { a10 += v0; a11 += v1; c1 += 1.f; }
    }
  }
  for (int j=0;j<d1;j++){
    int p = __shfl(pk1, j, 32);
    if (!PK_SELF(p)){
      int rel = PK_REL(p);
      unsigned hv = *(const unsigned*)&Hin[PK_SRC(p)*192 + 64 + rel*64 + o0];
      float v0 = bf2f((unsigned short)(hv & 0xFFFF));
      float v1 = bf2f((unsigned short)(hv >> 16));
      if (rel==0){ a00 += v0; a01 += v1; c0 += 1.f; } else { a10 += v0; a11 += v1; c1 += 1.f; }
    }
  }
  float i0 = 1.f/fmaxf(c0,1.f), i1 = 1.f/fmaxf(c1,1.f);
  sx[nl*64+o0]   = tanhf(bf2f(Hin[n*192+o0])   + rbias[o0]   + a00*i0 + a10*i1);
  sx[nl*64+o0+1] = tanhf(bf2f(Hin[n*192+o0+1]) + rbias[o0+1] + a01*i0 + a11*i1);
  __syncthreads();
  if (t < 192){
    float acc[8] = {0,0,0,0,0,0,0,0};
    for (int i=0;i<64;i++){
      float w = Wc[i*192 + t];
      #pragma unroll
      for (int tt=0;tt<8;tt++) acc[tt] += sx[tt*64+i]*w;
    }
    #pragma unroll
    for (int tt=0;tt<8;tt++) Hout[(n0+tt)*192 + t] = f2bf(acc[tt]);
  }
}

// ---- F3: ragg<64> (Hin stride 192) + nodemm 64x96 -> Hout [N,96] ----
__global__ void __launch_bounds__(256) k_f3(
    const unsigned short* __restrict__ Hin, const float* __restrict__ rbias,
    const int* __restrict__ degc, const int* __restrict__ pks,
    const float* __restrict__ Wc, unsigned short* __restrict__ Hout){
  __shared__ float sx[8*64];
  int n0 = blockIdx.x*8;
  int t = threadIdx.x, nl = t>>5, og = t&31, o0 = og*2, n = n0+nl;
  int r0 = n*CAP, deg = degc[n];
  int pk0 = (og      < deg) ? pks[r0 + og]      : 0x4000;
  int pk1 = (32 + og < deg) ? pks[r0 + 32 + og] : 0x4000;
  float a00=0.f, a01=0.f, a10=0.f, a11=0.f, c0=0.f, c1=0.f;
  int d0 = min(deg,32), d1 = deg - d0;
  for (int j=0;j<d0;j++){
    int p = __shfl(pk0, j, 32);
    if (!PK_SELF(p)){
      int rel = PK_REL(p);
      unsigned hv = *(const unsigned*)&Hin[PK_SRC(p)*192 + 64 + rel*64 + o0];
      float v0 = bf2f((unsigned short)(hv & 0xFFFF));
      float v1 = bf2f((unsigned short)(hv >> 16));
      if (rel==0){ a00 += v0; a01 += v1; c0 += 1.f; } else { a10 += v0; a11 += v1; c1 += 1.f; }
    }
  }
  for (int j=0;j<d1;j++){
    int p = __shfl(pk1, j, 32);
    if (!PK_SELF(p)){
      int rel = PK_REL(p);
      unsigned hv = *(const unsigned*)&Hin[PK_SRC(p)*192 + 64 + rel*64 + o0];
      float v0 = bf2f((unsigned short)(hv & 0xFFFF));
      float v1 = bf2f((unsigned short)(hv >> 16));
      if (rel==0){ a00 += v0; a01 += v1; c0 += 1.f; } else { a10 += v0; a11 += v1; c1 += 1.f; }
    }
  }
  float i0 = 1.f/fmaxf(c0,1.f), i1 = 1.f/fmaxf(c1,1.f);
  sx[nl*64+o0]   = tanhf(bf2f(Hin[n*192+o0])   + rbias[o0]   + a00*i0 + a10*i1);
  sx[nl*64+o0+1] = tanhf(bf2f(Hin[n*192+o0+1]) + rbias[o0+1] + a01*i0 + a11*i1);
  __syncthreads();
  if (t < 192){
    int c = t % 96, grp = t / 96;            // grp 0/1: nodes grp*4..+3
    float acc[4] = {0,0,0,0};
    for (int i=0;i<64;i++){
      float w = Wc[i*96 + c];
      #pragma unroll
      for (int tt=0;tt<4;tt++) acc[tt] += sx[(grp*4+tt)*64+i]*w;
    }
    #pragma unroll
    for (int tt=0;tt<4;tt++) Hout[(n0+grp*4+tt)*96 + c] = f2bf(acc[tt]);
  }
}

// ---- F4: ragg<32> (Hin stride 96) + GAT h=x@gw + scores ----
__global__ void __launch_bounds__(256) k_f4(
    const unsigned short* __restrict__ Hin, const float* __restrict__ rbias,
    const int* __restrict__ degc, const int* __restrict__ pks,
    const float* __restrict__ gw, const float* __restrict__ as_,
    const float* __restrict__ ad_,
    unsigned short* __restrict__ h16, float* __restrict__ asv, float* __restrict__ adv){
  __shared__ float sx[8*32];
  __shared__ float red[4][16];
  int n0 = blockIdx.x*8;
  int t = threadIdx.x, nl = t>>5, o = t&31, n = n0+nl;
  int r0 = n*CAP, deg = degc[n];
  int pk0 = (o      < deg) ? pks[r0 + o]      : 0x4000;
  int pk1 = (32 + o < deg) ? pks[r0 + 32 + o] : 0x4000;
  float a0=0.f, a1=0.f, c0=0.f, c1=0.f;
  int d0 = min(deg,32), d1 = deg - d0;
  for (int j=0;j<d0;j++){
    int p = __shfl(pk0, j, 32);
    if (!PK_SELF(p)){
      int rel = PK_REL(p);
      float v = bf2f(Hin[PK_SRC(p)*96 + 32 + rel*32 + o]);
      if (rel==0){ a0 += v; c0 += 1.f; } else { a1 += v; c1 += 1.f; }
    }
  }
  for (int j=0;j<d1;j++){
    int p = __shfl(pk1, j, 32);
    if (!PK_SELF(p)){
      int rel = PK_REL(p);
      float v = bf2f(Hin[PK_SRC(p)*96 + 32 + rel*32 + o]);
      if (rel==0){ a0 += v; c0 += 1.f; } else { a1 += v; c1 += 1.f; }
    }
  }
  sx[nl*32+o] = tanhf(bf2f(Hin[n*96+o]) + rbias[o]
                      + a0/fmaxf(c0,1.f) + a1/fmaxf(c1,1.f));
  __syncthreads();
  int c2 = t*2;
  float2 acc[8];
  #pragma unroll
  for (int k=0;k<8;k++) acc[k] = {0.f,0.f};
  for (int i=0;i<32;i++){
    const float2 g = *(const float2*)&gw[i*512 + c2];
    #pragma unroll
    for (int k=0;k<8;k++){
      float xv = sx[k*32+i];
      acc[k].x += xv*g.x; acc[k].y += xv*g.y;
    }
  }
  const float2 a2 = *(const float2*)&as_[c2];
  const float2 d2 = *(const float2*)&ad_[c2];
  float sa[8], sd[8];
  #pragma unroll
  for (int k=0;k<8;k++){
    ushort2 ov;
    ov.x = f2bf(acc[k].x); ov.y = f2bf(acc[k].y);
    *(ushort2*)&h16[(n0+k)*512 + c2] = ov;
    sa[k] = acc[k].x*a2.x + acc[k].y*a2.y;
    sd[k] = acc[k].x*d2.x + acc[k].y*d2.y;
  }
  #pragma unroll
  for (int m=32;m>0;m>>=1){
    #pragma unroll
    for (int k=0;k<8;k++){ sa[k] += __shfl_xor(sa[k],m,64); sd[k] += __shfl_xor(sd[k],m,64); }
  }
  int wv = t>>6;
  if ((t&63)==0){
    #pragma unroll
    for (int k=0;k<8;k++){ red[wv][k]=sa[k]; red[wv][8+k]=sd[k]; }
  }
  __syncthreads();
  if (t<8)        asv[n0+t]   = red[0][t]+red[1][t]+red[2][t]+red[3][t];
  else if (t<16)  adv[n0+t-8] = red[0][t]+red[1][t]+red[2][t]+red[3][t];
}

// fused softmax + aggregation + bias + relu: 1 wave per node (6000 blocks).
// Shuffle-only (no LDS staging, no __syncthreads): deg <= 64 so the whole CSR
// row fits one register per lane; per-edge coef/src come via __shfl broadcast.
__global__ void __launch_bounds__(64) k_gsa(
    const int* __restrict__ degc, const int* __restrict__ pks,
    const float* __restrict__ asv, const float* __restrict__ adv,
    const unsigned short* __restrict__ h16, const float* __restrict__ bias,
    unsigned short* __restrict__ gout16){
  int n = blockIdx.x;
  int lane = threadIdx.x;
  int r0 = n*CAP, deg = degc[n];
  float advn = adv[n];
  int pk  = (lane < deg) ? pks[r0 + lane] : -1;
  int src = (pk >= 0) ? PK_SRC(pk) : 0;
  float aa = -1e30f;
  if (pk >= 0){
    float a = asv[src] + advn;
    aa = (a >= 0.f) ? a : 0.2f*a;
  }
  float m = aa;
  #pragma unroll
  for (int off=32;off>0;off>>=1) m = fmaxf(m, __shfl_xor(m,off,64));
  float ex = (pk >= 0) ? expf(aa - m) : 0.f;
  float sumex = ex;
  #pragma unroll
  for (int off=32;off>0;off>>=1) sumex += __shfl_xor(sumex,off,64);
  float acc[8] = {0,0,0,0,0,0,0,0};
  for (int e=0;e<deg;e++){
    float cf = __shfl(ex, e, 64);
    int s    = __shfl(src, e, 64);
    const u16x8 hv = *(const u16x8*)&h16[(size_t)s*512 + lane*8];
    #pragma unroll
    for (int q=0;q<8;q++) acc[q] += cf * bf2f(hv[q]);
  }
  float inv = 1.f / fmaxf(sumex, 1e-16f);
  const float4 b0 = *(const float4*)&bias[lane*8];
  const float4 b1v = *(const float4*)&bias[lane*8+4];
  u16x8 o;
  o[0] = f2bf(fmaxf(acc[0]*inv + b0.x, 0.f));
  o[1] = f2bf(fmaxf(acc[1]*inv + b0.y, 0.f));
  o[2] = f2bf(fmaxf(acc[2]*inv + b0.z, 0.f));
  o[3] = f2bf(fmaxf(acc[3]*inv + b0.w, 0.f));
  o[4] = f2bf(fmaxf(acc[4]*inv + b1v.x, 0.f));
  o[5] = f2bf(fmaxf(acc[5]*inv + b1v.y, 0.f));
  o[6] = f2bf(fmaxf(acc[6]*inv + b1v.z, 0.f));
  o[7] = f2bf(fmaxf(acc[7]*inv + b1v.w, 0.f));
  *(u16x8*)&gout16[(size_t)n*512 + lane*8] = o;
}

// ---- edge MLP precompute via MFMA: P16[6000][256] = gout16 @ Bt16^T (bf16 out) ----
__global__ void __launch_bounds__(64) k_AB(const unsigned short* __restrict__ gout16,
                                           const unsigned short* __restrict__ Bt16,
                                           unsigned short* __restrict__ P16){
  int lane = threadIdx.x;
  int mt = blockIdx.x >> 2;        // 375 row tiles
  int nt = blockIdx.x & 3;         // 4 col groups of 64
  int kq = (lane >> 4) * 8;
  const unsigned short* arow = gout16 + (size_t)(mt*16 + (lane & 15))*512 + kq;
  const unsigned short* bbase = Bt16 + (size_t)(nt*64 + (lane & 15))*512 + kq;
  f32x4 acc0 = {0,0,0,0}, acc1 = {0,0,0,0}, acc2 = {0,0,0,0}, acc3 = {0,0,0,0};
  for (int k = 0; k < 512; k += 32){
    frag8 a = *(const frag8*)(arow + k);
    frag8 b0 = *(const frag8*)(bbase + k);
    frag8 b1 = *(const frag8*)(bbase + 16*512 + k);
    frag8 b2 = *(const frag8*)(bbase + 32*512 + k);
    frag8 b3 = *(const frag8*)(bbase + 48*512 + k);
    acc0 = __builtin_amdgcn_mfma_f32_16x16x32_bf16(a, b0, acc0, 0, 0, 0);
    acc1 = __builtin_amdgcn_mfma_f32_16x16x32_bf16(a, b1, acc1, 0, 0, 0);
    acc2 = __builtin_amdgcn_mfma_f32_16x16x32_bf16(a, b2, acc2, 0, 0, 0);
    acc3 = __builtin_amdgcn_mfma_f32_16x16x32_bf16(a, b3, acc3, 0, 0, 0);
  }
  int rowb = mt*16 + (lane >> 4)*4;
  int col  = nt*64 + (lane & 15);
  #pragma unroll
  for (int i=0;i<4;i++){
    P16[(size_t)(rowb+i)*256 + col     ] = f2bf(acc0[i]);
    P16[(size_t)(rowb+i)*256 + col + 16] = f2bf(acc1[i]);
    P16[(size_t)(rowb+i)*256 + col + 32] = f2bf(acc2[i]);
    P16[(size_t)(rowb+i)*256 + col + 48] = f2bf(acc3[i]);
  }
}

// per-edge MLP head: 16 lanes/edge, bf16 P loads
__global__ void k_edge(const int* __restrict__ ei, const unsigned short* __restrict__ P16,
                       const float* __restrict__ b1,
                       const float* __restrict__ w2, const float* __restrict__ b2,
                       float* __restrict__ out){
  int e = blockIdx.x*16 + (threadIdx.x >> 4);
  int l = threadIdx.x & 15;            // lane covers channels [l*8, l*8+8)
  if (e >= EE) return;
  int s = ei[e], d = ei[EE+e];
  const u16x8 Av = *(const u16x8*)&P16[(size_t)s*256 + l*8];
  const u16x8 Bv = *(const u16x8*)&P16[(size_t)d*256 + 128 + l*8];
  const float4 b1a = *(const float4*)&b1[l*8];
  const float4 b1b = *(const float4*)&b1[l*8+4];
  const float4 w2a = *(const float4*)&w2[l*8];
  const float4 w2b = *(const float4*)&w2[l*8+4];
  float h0 = fmaxf(bf2f(Av[0])+bf2f(Bv[0])+b1a.x, 0.f);
  float h1 = fmaxf(bf2f(Av[1])+bf2f(Bv[1])+b1a.y, 0.f);
  float h2 = fmaxf(bf2f(Av[2])+bf2f(Bv[2])+b1a.z, 0.f);
  float h3 = fmaxf(bf2f(Av[3])+bf2f(Bv[3])+b1a.w, 0.f);
  float h4 = fmaxf(bf2f(Av[4])+bf2f(Bv[4])+b1b.x, 0.f);
  float h5 = fmaxf(bf2f(Av[5])+bf2f(Bv[5])+b1b.y, 0.f);
  float h6 = fmaxf(bf2f(Av[6])+bf2f(Bv[6])+b1b.z, 0.f);
  float h7 = fmaxf(bf2f(Av[7])+bf2f(Bv[7])+b1b.w, 0.f);
  float acc = h0*w2a.x + h1*w2a.y + h2*w2a.z + h3*w2a.w
            + h4*w2b.x + h5*w2b.y + h6*w2b.z + h7*w2b.w;
  #pragma unroll
  for (int m=8;m>0;m>>=1) acc += __shfl_xor(acc,m,64);
  if (l==0) out[e] = 1.f/(1.f + expf(-(acc + b2[0])));
}

extern "C" void kernel_launch(void* const* d_in, const int* in_sizes, int n_in,
                              void* d_out, int out_size, void* d_ws, size_t ws_size,
                              hipStream_t stream){
  const float* basis0 = (const float*)d_in[0];
  const float* comp0  = (const float*)d_in[1];
  const float* root0  = (const float*)d_in[2];
  const float* rbias0 = (const float*)d_in[3];
  const float* basis1 = (const float*)d_in[4];
  const float* comp1  = (const float*)d_in[5];
  const float* root1  = (const float*)d_in[6];
  const float* rbias1 = (const float*)d_in[7];
  const float* basis2 = (const float*)d_in[8];
  const float* comp2  = (const float*)d_in[9];
  const float* root2  = (const float*)d_in[10];
  const float* rbias2 = (const float*)d_in[11];
  const float* basis3 = (const float*)d_in[12];
  const float* comp3  = (const float*)d_in[13];
  const float* root3  = (const float*)d_in[14];
  const float* rbias3 = (const float*)d_in[15];
  const float* gat_w = (const float*)d_in[16];
  const float* a_src = (const float*)d_in[17];
  const float* a_dst = (const float*)d_in[18];
  const float* gat_b = (const float*)d_in[19];
  const float* w1 = (const float*)d_in[20];
  const float* b1 = (const float*)d_in[21];
  const float* w2 = (const float*)d_in[22];
  const float* b2 = (const float*)d_in[23];
  const int* ei = (const int*)d_in[24];
  const int* et = (const int*)d_in[25];
  float* out = (float*)d_out;

  // workspace carve-up (16B-aligned sections)
  float* p = (float*)d_ws;
  int* cursor = (int*)p; p += NN;              // doubles as degree after k_pdc
  int* pks    = (int*)p; p += NN*CAP;          // bucket CSR (64 slots/node)
  unsigned short* W016 = (unsigned short*)p; p += NN*32;       // 2*NN*32 bf16
  float* Wcat = p; p += 24576;
  unsigned short* Bt16 = (unsigned short*)p; p += 256*512/2;
  unsigned short* H16a = (unsigned short*)p; p += NN*96;       // NN*192 bf16
  unsigned short* H16b = (unsigned short*)p; p += NN*96;       // NN*192 bf16
  unsigned short* h16  = (unsigned short*)p; p += NN*256;      // NN*512 bf16
  float* asv  = p; p += NN;
  float* adv  = p; p += NN;
  unsigned short* gout16 = (unsigned short*)p; p += NN*256;    // NN*512 bf16
  unsigned short* P16 = (unsigned short*)p; p += NN*128;       // NN*256 bf16

  auto grid = [](long long n){ return dim3((unsigned)((n + 255)/256)); };

  // ---- zero cursor only, then single fused prep kernel ----
  hipMemsetAsync(cursor, 0, (size_t)NN*sizeof(int), stream);
  k_pdc<<<grid(2LL*NN*32 + 24576 + 256*512),256,0,stream>>>(ei, et, cursor, pks,
        basis0, comp0, basis1,comp1,root1, basis2,comp2,root2,
        basis3,comp3,root3, w1, W016, Wcat, Bt16);

  // ---- RGCN stack (fused gather+mm per layer; rel-counts derived locally) ----
  k_f1<<<dim3(NN/8),256,0,stream>>>(W016, root0, rbias0, cursor, pks, Wcat, H16a);
  k_f2<<<dim3(NN/8),256,0,stream>>>(H16a, rbias1, cursor, pks, Wcat + 6144, H16b);
  k_f3<<<dim3(NN/8),256,0,stream>>>(H16b, rbias2, cursor, pks, Wcat + 18432, H16a);
  k_f4<<<dim3(NN/8),256,0,stream>>>(H16a, rbias3, cursor, pks,
                                    gat_w, a_src, a_dst, h16, asv, adv);

  // ---- GAT softmax+aggregate (1 wave/node) ----
  k_gsa<<<dim3(NN),64,0,stream>>>(cursor, pks, asv, adv, h16, gat_b, gout16);

  // ---- edge MLP: MFMA GEMM then per-edge head ----
  k_AB<<<dim3(1500),64,0,stream>>>(gout16, Bt16, P16);
  k_edge<<<dim3((EE+15)/16),256,0,stream>>>(ei, P16, b1, w2, b2, out);
}

// Round 5
// 204.803 us; speedup vs baseline: 3.7998x; 1.0570x over previous
//
#include <hip/hip_runtime.h>
#include <math.h>

#define NN 6000
#define EE 100000
#define ELL (EE + NN)   // edges + self loops for GAT
#define CAP 64          // bucket-CSR capacity per node (max deg ~45 << 64)

// packed CSR entry: src (13b) | rel<<13 | self<<14
#define PK_SRC(p)  ((p) & 0x1FFF)
#define PK_REL(p)  (((p) >> 13) & 1)
#define PK_SELF(p) ((p) & 0x4000)

typedef __attribute__((ext_vector_type(8))) short frag8;           // 8 bf16 (4 VGPR)
typedef __attribute__((ext_vector_type(4))) float f32x4;
typedef __attribute__((ext_vector_type(8))) unsigned short u16x8;  // 16B of bf16

__device__ __forceinline__ unsigned short f2bf(float f){
  unsigned u = __float_as_uint(f);
  unsigned r = u + 0x7FFFu + ((u >> 16) & 1u);   // round-to-nearest-even
  return (unsigned short)(r >> 16);
}
__device__ __forceinline__ float bf2f(unsigned short s){
  return __uint_as_float(((unsigned)s) << 16);
}

// ---- fused: bucket-CSR fill + weight prep (W0 bf16) + w1->Bt bf16 ----
// cursor[] doubles as the per-node degree after this kernel completes.
__global__ void k_pdc(const int* __restrict__ ei, const int* __restrict__ et,
                      int* __restrict__ cursor, int* __restrict__ pks,
                      const float* __restrict__ basis0, const float* __restrict__ comp0,
                      const float* __restrict__ b1,const float* __restrict__ c1,const float* __restrict__ r1,
                      const float* __restrict__ b2,const float* __restrict__ c2,const float* __restrict__ r2,
                      const float* __restrict__ b3,const float* __restrict__ c3,const float* __restrict__ r3,
                      const float* __restrict__ w1,
                      unsigned short* __restrict__ W016, float* __restrict__ Wcat,
                      unsigned short* __restrict__ Bt16){
  int t0 = blockIdx.x*256 + threadIdx.x;
  if (t0 < ELL){
    int d, pk;
    if (t0 < EE){
      d = ei[EE+t0];
      pk = ei[t0] | (et[t0] << 13);
    } else {
      d = t0 - EE; pk = d | 0x4000;
    }
    int pos = atomicAdd(&cursor[d], 1);
    pks[d*CAP + pos] = pk;
  }
  if (t0 < 2*NN*32){
    int r = t0 / (NN*32);
    int no = t0 - r*(NN*32);
    float acc = 0.f;
    #pragma unroll
    for (int b=0;b<4;b++) acc += comp0[r*4+b] * basis0[b*(NN*32)+no];
    W016[t0] = f2bf(acc);
    return;
  }
  int tw = t0 - 2*NN*32;
  if (tw < 24576){
    const float *bb,*cc,*rr; int I,O; int t = tw;
    if (tw < 6144)        { bb=b1;cc=c1;rr=r1;I=32;O=64; }
    else if (tw < 18432)  { bb=b2;cc=c2;rr=r2;I=64;O=64; t -= 6144; }
    else                  { bb=b3;cc=c3;rr=r3;I=64;O=32; t -= 18432; }
    int C = 3*O;
    int i = t / C; int col = t - i*C;
    float v;
    if (col < O) v = rr[i*O + col];
    else {
      int r = (col - O) / O; int o = col - O - r*O;
      v = 0.f;
      #pragma unroll
      for (int b=0;b<4;b++) v += cc[r*4+b]*bb[(b*I+i)*O + o];
    }
    Wcat[tw] = v;
    return;
  }
  int tb = tw - 24576;           // Bt16: [n][k], n in [0,256), k in [0,512)
  if (tb >= 256*512) return;
  int n = tb >> 9, k = tb & 511;
  float v = (n < 128) ? w1[k*128 + n] : w1[(512+k)*128 + (n-128)];
  Bt16[tb] = f2bf(v);
}

// ---- F1: layer-0 gather (x=I) + layer-1 nodemm -> H16 [N,192] ----
// Pair-unrolled gather: both payload loads of (j, j+1) issue before either
// accumulate (2 outstanding loads/iter). Slots >= deg are self-tagged, so the
// j+1 probe auto-skips; accumulation order is unchanged (A then B).
__global__ void __launch_bounds__(256) k_f1(
    const unsigned short* __restrict__ W016, const float* __restrict__ root,
    const float* __restrict__ rbias0,
    const int* __restrict__ degc, const int* __restrict__ pks,
    const float* __restrict__ Wc, unsigned short* __restrict__ Hout){
  __shared__ float sx[8*32];
  int n0 = blockIdx.x*8;
  int t = threadIdx.x, nl = t>>5, o = t&31, n = n0+nl;
  int r0 = n*CAP, deg = degc[n];
  int pk0 = (o      < deg) ? pks[r0 + o]      : 0x4000;   // self => skipped
  int pk1 = (32 + o < deg) ? pks[r0 + 32 + o] : 0x4000;
  float a0 = 0.f, a1 = 0.f, c0 = 0.f, c1 = 0.f;
  int d0 = min(deg,32), d1 = deg - d0;
  for (int j=0;j<d0;j+=2){
    int pA = __shfl(pk0, j, 32);
    int pB = __shfl(pk0, j+1, 32);      // j+1<=31; slot>=deg is self-tagged
    float vA = bf2f(W016[(PK_REL(pA)*NN + PK_SRC(pA))*32 + o]);
    float vB = bf2f(W016[(PK_REL(pB)*NN + PK_SRC(pB))*32 + o]);
    if (!PK_SELF(pA)){ if (PK_REL(pA)==0){ a0 += vA; c0 += 1.f; } else { a1 += vA; c1 += 1.f; } }
    if (!PK_SELF(pB)){ if (PK_REL(pB)==0){ a0 += vB; c0 += 1.f; } else { a1 += vB; c1 += 1.f; } }
  }
  for (int j=0;j<d1;j+=2){
    int pA = __shfl(pk1, j, 32);
    int pB = __shfl(pk1, j+1, 32);
    float vA = bf2f(W016[(PK_REL(pA)*NN + PK_SRC(pA))*32 + o]);
    float vB = bf2f(W016[(PK_REL(pB)*NN + PK_SRC(pB))*32 + o]);
    if (!PK_SELF(pA)){ if (PK_REL(pA)==0){ a0 += vA; c0 += 1.f; } else { a1 += vA; c1 += 1.f; } }
    if (!PK_SELF(pB)){ if (PK_REL(pB)==0){ a0 += vB; c0 += 1.f; } else { a1 += vB; c1 += 1.f; } }
  }
  sx[nl*32+o] = tanhf(root[n*32+o] + rbias0[o]
                      + a0/fmaxf(c0,1.f) + a1/fmaxf(c1,1.f));
  __syncthreads();
  if (t < 192){
    float acc[8] = {0,0,0,0,0,0,0,0};
    for (int i=0;i<32;i++){
      float w = Wc[i*192 + t];
      #pragma unroll
      for (int tt=0;tt<8;tt++) acc[tt] += sx[tt*32+i]*w;
    }
    #pragma unroll
    for (int tt=0;tt<8;tt++) Hout[(n0+tt)*192 + t] = f2bf(acc[tt]);
  }
}

// ---- F2: ragg<64> (Hin stride 192) + nodemm 64x192 -> Hout [N,192] ----
__global__ void __launch_bounds__(256) k_f2(
    const unsigned short* __restrict__ Hin, const float* __restrict__ rbias,
    const int* __restrict__ degc, const int* __restrict__ pks,
    const float* __restrict__ Wc, unsigned short* __restrict__ Hout){
  __shared__ float sx[8*64];
  int n0 = blockIdx.x*8;
  int t = threadIdx.x, nl = t>>5, og = t&31, o0 = og*2, n = n0+nl;
  int r0 = n*CAP, deg = degc[n];
  int pk0 = (og      < deg) ? pks[r0 + og]      : 0x4000;
  int pk1 = (32 + og < deg) ? pks[r0 + 32 + og] : 0x4000;
  float a00=0.f, a01=0.f, a10=0.f, a11=0.f, c0=0.f, c1=0.f;
  int d0 = min(deg,32), d1 = deg - d0;
  for (int j=0;j<d0;j+=2){
    int pA = __shfl(pk0, j, 32);
    int pB = __shfl(pk0, j+1, 32);
    unsigned hvA = *(const unsigned*)&Hin[PK_SRC(pA)*192 + 64 + PK_REL(pA)*64 + o0];
    unsigned hvB = *(const unsigned*)&Hin[PK_SRC(pB)*192 + 64 + PK_REL(pB)*64 + o0];
    if (!PK_SELF(pA)){
      float v0 = bf2f((unsigned short)(hvA & 0xFFFF));
      float v1 = bf2f((unsigned short)(hvA >> 16));
      if (PK_REL(pA)==0){ a00 += v0; a01 += v1; c0 += 1.f; } else { a10 += v0; a11 += v1; c1 += 1.f; }
    }
    if (!PK_SELF(pB)){
      float v0 = bf2f((unsigned short)(hvB & 0xFFFF));
      float v1 = bf2f((unsigned short)(hvB >> 16));
      if (PK_REL(pB)==0){ a00 += v0; a01 += v1; c0 += 1.f; } else { a10 += v0; a11 += v1; c1 += 1.f; }
    }
  }
  for (int j=0;j<d1;j+=2){
    int pA = __shfl(pk1, j, 32);
    int pB = __shfl(pk1, j+1, 32);
    unsigned hvA = *(const unsigned*)&Hin[PK_SRC(pA)*192 + 64 + PK_REL(pA)*64 + o0];
    unsigned hvB = *(const unsigned*)&Hin[PK_SRC(pB)*192 + 64 + PK_REL(pB)*64 + o0];
    if (!PK_SELF(pA)){
      float v0 = bf2f((unsigned short)(hvA & 0xFFFF));
      float v1 = bf2f((unsigned short)(hvA >> 16));
      if (PK_REL(pA)==0){ a00 += v0; a01 += v1; c0 += 1.f; } else { a10 += v0; a11 += v1; c1 += 1.f; }
    }
    if (!PK_SELF(pB)){
      float v0 = bf2f((unsigned short)(hvB & 0xFFFF));
      float v1 = bf2f((unsigned short)(hvB >> 16));
      if (PK_REL(pB)==0){ a00 += v0; a01 += v1; c0 += 1.f; } else { a10 += v0; a11 += v1; c1 += 1.f; }
    }
  }
  float i0 = 1.f/fmaxf(c0,1.f), i1 = 1.f/fmaxf(c1,1.f);
  sx[nl*64+o0]   = tanhf(bf2f(Hin[n*192+o0])   + rbias[o0]   + a00*i0 + a10*i1);
  sx[nl*64+o0+1] = tanhf(bf2f(Hin[n*192+o0+1]) + rbias[o0+1] + a01*i0 + a11*i1);
  __syncthreads();
  if (t < 192){
    float acc[8] = {0,0,0,0,0,0,0,0};
    for (int i=0;i<64;i++){
      float w = Wc[i*192 + t];
      #pragma unroll
      for (int tt=0;tt<8;tt++) acc[tt] += sx[tt*64+i]*w;
    }
    #pragma unroll
    for (int tt=0;tt<8;tt++) Hout[(n0+tt)*192 + t] = f2bf(acc[tt]);
  }
}

// ---- F3: ragg<64> (Hin stride 192) + nodemm 64x96 -> Hout [N,96] ----
__global__ void __launch_bounds__(256) k_f3(
    const unsigned short* __restrict__ Hin, const float* __restrict__ rbias,
    const int* __restrict__ degc, const int* __restrict__ pks,
    const float* __restrict__ Wc, unsigned short* __restrict__ Hout){
  __shared__ float sx[8*64];
  int n0 = blockIdx.x*8;
  int t = threadIdx.x, nl = t>>5, og = t&31, o0 = og*2, n = n0+nl;
  int r0 = n*CAP, deg = degc[n];
  int pk0 = (og      < deg) ? pks[r0 + og]      : 0x4000;
  int pk1 = (32 + og < deg) ? pks[r0 + 32 + og] : 0x4000;
  float a00=0.f, a01=0.f, a10=0.f, a11=0.f, c0=0.f, c1=0.f;
  int d0 = min(deg,32), d1 = deg - d0;
  for (int j=0;j<d0;j+=2){
    int pA = __shfl(pk0, j, 32);
    int pB = __shfl(pk0, j+1, 32);
    unsigned hvA = *(const unsigned*)&Hin[PK_SRC(pA)*192 + 64 + PK_REL(pA)*64 + o0];
    unsigned hvB = *(const unsigned*)&Hin[PK_SRC(pB)*192 + 64 + PK_REL(pB)*64 + o0];
    if (!PK_SELF(pA)){
      float v0 = bf2f((unsigned short)(hvA & 0xFFFF));
      float v1 = bf2f((unsigned short)(hvA >> 16));
      if (PK_REL(pA)==0){ a00 += v0; a01 += v1; c0 += 1.f; } else { a10 += v0; a11 += v1; c1 += 1.f; }
    }
    if (!PK_SELF(pB)){
      float v0 = bf2f((unsigned short)(hvB & 0xFFFF));
      float v1 = bf2f((unsigned short)(hvB >> 16));
      if (PK_REL(pB)==0){ a00 += v0; a01 += v1; c0 += 1.f; } else { a10 += v0; a11 += v1; c1 += 1.f; }
    }
  }
  for (int j=0;j<d1;j+=2){
    int pA = __shfl(pk1, j, 32);
    int pB = __shfl(pk1, j+1, 32);
    unsigned hvA = *(const unsigned*)&Hin[PK_SRC(pA)*192 + 64 + PK_REL(pA)*64 + o0];
    unsigned hvB = *(const unsigned*)&Hin[PK_SRC(pB)*192 + 64 + PK_REL(pB)*64 + o0];
    if (!PK_SELF(pA)){
      float v0 = bf2f((unsigned short)(hvA & 0xFFFF));
      float v1 = bf2f((unsigned short)(hvA >> 16));
      if (PK_REL(pA)==0){ a00 += v0; a01 += v1; c0 += 1.f; } else { a10 += v0; a11 += v1; c1 += 1.f; }
    }
    if (!PK_SELF(pB)){
      float v0 = bf2f((unsigned short)(hvB & 0xFFFF));
      float v1 = bf2f((unsigned short)(hvB >> 16));
      if (PK_REL(pB)==0){ a00 += v0; a01 += v1; c0 += 1.f; } else { a10 += v0; a11 += v1; c1 += 1.f; }
    }
  }
  float i0 = 1.f/fmaxf(c0,1.f), i1 = 1.f/fmaxf(c1,1.f);
  sx[nl*64+o0]   = tanhf(bf2f(Hin[n*192+o0])   + rbias[o0]   + a00*i0 + a10*i1);
  sx[nl*64+o0+1] = tanhf(bf2f(Hin[n*192+o0+1]) + rbias[o0+1] + a01*i0 + a11*i1);
  __syncthreads();
  if (t < 192){
    int c = t % 96, grp = t / 96;            // grp 0/1: nodes grp*4..+3
    float acc[4] = {0,0,0,0};
    for (int i=0;i<64;i++){
      float w = Wc[i*96 + c];
      #pragma unroll
      for (int tt=0;tt<4;tt++) acc[tt] += sx[(grp*4+tt)*64+i]*w;
    }
    #pragma unroll
    for (int tt=0;tt<4;tt++) Hout[(n0+grp*4+tt)*96 + c] = f2bf(acc[tt]);
  }
}

// ---- F4: ragg<32> (Hin stride 96) + GAT h=x@gw + scores ----
__global__ void __launch_bounds__(256) k_f4(
    const unsigned short* __restrict__ Hin, const float* __restrict__ rbias,
    const int* __restrict__ degc, const int* __restrict__ pks,
    const float* __restrict__ gw, const float* __restrict__ as_,
    const float* __restrict__ ad_,
    unsigned short* __restrict__ h16, float* __restrict__ asv, float* __restrict__ adv){
  __shared__ float sx[8*32];
  __shared__ float red[4][16];
  int n0 = blockIdx.x*8;
  int t = threadIdx.x, nl = t>>5, o = t&31, n = n0+nl;
  int r0 = n*CAP, deg = degc[n];
  int pk0 = (o      < deg) ? pks[r0 + o]      : 0x4000;
  int pk1 = (32 + o < deg) ? pks[r0 + 32 + o] : 0x4000;
  float a0=0.f, a1=0.f, c0=0.f, c1=0.f;
  int d0 = min(deg,32), d1 = deg - d0;
  for (int j=0;j<d0;j+=2){
    int pA = __shfl(pk0, j, 32);
    int pB = __shfl(pk0, j+1, 32);
    float vA = bf2f(Hin[PK_SRC(pA)*96 + 32 + PK_REL(pA)*32 + o]);
    float vB = bf2f(Hin[PK_SRC(pB)*96 + 32 + PK_REL(pB)*32 + o]);
    if (!PK_SELF(pA)){ if (PK_REL(pA)==0){ a0 += vA; c0 += 1.f; } else { a1 += vA; c1 += 1.f; } }
    if (!PK_SELF(pB)){ if (PK_REL(pB)==0){ a0 += vB; c0 += 1.f; } else { a1 += vB; c1 += 1.f; } }
  }
  for (int j=0;j<d1;j+=2){
    int pA = __shfl(pk1, j, 32);
    int pB = __shfl(pk1, j+1, 32);
    float vA = bf2f(Hin[PK_SRC(pA)*96 + 32 + PK_REL(pA)*32 + o]);
    float vB = bf2f(Hin[PK_SRC(pB)*96 + 32 + PK_REL(pB)*32 + o]);
    if (!PK_SELF(pA)){ if (PK_REL(pA)==0){ a0 += vA; c0 += 1.f; } else { a1 += vA; c1 += 1.f; } }
    if (!PK_SELF(pB)){ if (PK_REL(pB)==0){ a0 += vB; c0 += 1.f; } else { a1 += vB; c1 += 1.f; } }
  }
  sx[nl*32+o] = tanhf(bf2f(Hin[n*96+o]) + rbias[o]
                      + a0/fmaxf(c0,1.f) + a1/fmaxf(c1,1.f));
  __syncthreads();
  int c2 = t*2;
  float2 acc[8];
  #pragma unroll
  for (int k=0;k<8;k++) acc[k] = {0.f,0.f};
  for (int i=0;i<32;i++){
    const float2 g = *(const float2*)&gw[i*512 + c2];
    #pragma unroll
    for (int k=0;k<8;k++){
      float xv = sx[k*32+i];
      acc[k].x += xv*g.x; acc[k].y += xv*g.y;
    }
  }
  const float2 a2 = *(const float2*)&as_[c2];
  const float2 d2 = *(const float2*)&ad_[c2];
  float sa[8], sd[8];
  #pragma unroll
  for (int k=0;k<8;k++){
    ushort2 ov;
    ov.x = f2bf(acc[k].x); ov.y = f2bf(acc[k].y);
    *(ushort2*)&h16[(n0+k)*512 + c2] = ov;
    sa[k] = acc[k].x*a2.x + acc[k].y*a2.y;
    sd[k] = acc[k].x*d2.x + acc[k].y*d2.y;
  }
  #pragma unroll
  for (int m=32;m>0;m>>=1){
    #pragma unroll
    for (int k=0;k<8;k++){ sa[k] += __shfl_xor(sa[k],m,64); sd[k] += __shfl_xor(sd[k],m,64); }
  }
  int wv = t>>6;
  if ((t&63)==0){
    #pragma unroll
    for (int k=0;k<8;k++){ red[wv][k]=sa[k]; red[wv][8+k]=sd[k]; }
  }
  __syncthreads();
  if (t<8)        asv[n0+t]   = red[0][t]+red[1][t]+red[2][t]+red[3][t];
  else if (t<16)  adv[n0+t-8] = red[0][t]+red[1][t]+red[2][t]+red[3][t];
}

// fused softmax + aggregation + bias + relu: 1 wave per node (6000 blocks).
// Shuffle-only (no LDS staging, no __syncthreads): deg <= 64 so the whole CSR
// row fits one register per lane; per-edge coef/src come via __shfl broadcast.
__global__ void __launch_bounds__(64) k_gsa(
    const int* __restrict__ degc, const int* __restrict__ pks,
    const float* __restrict__ asv, const float* __restrict__ adv,
    const unsigned short* __restrict__ h16, const float* __restrict__ bias,
    unsigned short* __restrict__ gout16){
  int n = blockIdx.x;
  int lane = threadIdx.x;
  int r0 = n*CAP, deg = degc[n];
  float advn = adv[n];
  int pk  = (lane < deg) ? pks[r0 + lane] : -1;
  int src = (pk >= 0) ? PK_SRC(pk) : 0;
  float aa = -1e30f;
  if (pk >= 0){
    float a = asv[src] + advn;
    aa = (a >= 0.f) ? a : 0.2f*a;
  }
  float m = aa;
  #pragma unroll
  for (int off=32;off>0;off>>=1) m = fmaxf(m, __shfl_xor(m,off,64));
  float ex = (pk >= 0) ? expf(aa - m) : 0.f;
  float sumex = ex;
  #pragma unroll
  for (int off=32;off>0;off>>=1) sumex += __shfl_xor(sumex,off,64);
  float acc[8] = {0,0,0,0,0,0,0,0};
  for (int e=0;e<deg;e++){
    float cf = __shfl(ex, e, 64);
    int s    = __shfl(src, e, 64);
    const u16x8 hv = *(const u16x8*)&h16[(size_t)s*512 + lane*8];
    #pragma unroll
    for (int q=0;q<8;q++) acc[q] += cf * bf2f(hv[q]);
  }
  float inv = 1.f / fmaxf(sumex, 1e-16f);
  const float4 b0 = *(const float4*)&bias[lane*8];
  const float4 b1v = *(const float4*)&bias[lane*8+4];
  u16x8 o;
  o[0] = f2bf(fmaxf(acc[0]*inv + b0.x, 0.f));
  o[1] = f2bf(fmaxf(acc[1]*inv + b0.y, 0.f));
  o[2] = f2bf(fmaxf(acc[2]*inv + b0.z, 0.f));
  o[3] = f2bf(fmaxf(acc[3]*inv + b0.w, 0.f));
  o[4] = f2bf(fmaxf(acc[4]*inv + b1v.x, 0.f));
  o[5] = f2bf(fmaxf(acc[5]*inv + b1v.y, 0.f));
  o[6] = f2bf(fmaxf(acc[6]*inv + b1v.z, 0.f));
  o[7] = f2bf(fmaxf(acc[7]*inv + b1v.w, 0.f));
  *(u16x8*)&gout16[(size_t)n*512 + lane*8] = o;
}

// ---- edge MLP precompute via MFMA: P16[6000][256] = gout16 @ Bt16^T (bf16 out) ----
__global__ void __launch_bounds__(64) k_AB(const unsigned short* __restrict__ gout16,
                                           const unsigned short* __restrict__ Bt16,
                                           unsigned short* __restrict__ P16){
  int lane = threadIdx.x;
  int mt = blockIdx.x >> 2;        // 375 row tiles
  int nt = blockIdx.x & 3;         // 4 col groups of 64
  int kq = (lane >> 4) * 8;
  const unsigned short* arow = gout16 + (size_t)(mt*16 + (lane & 15))*512 + kq;
  const unsigned short* bbase = Bt16 + (size_t)(nt*64 + (lane & 15))*512 + kq;
  f32x4 acc0 = {0,0,0,0}, acc1 = {0,0,0,0}, acc2 = {0,0,0,0}, acc3 = {0,0,0,0};
  for (int k = 0; k < 512; k += 32){
    frag8 a = *(const frag8*)(arow + k);
    frag8 b0 = *(const frag8*)(bbase + k);
    frag8 b1 = *(const frag8*)(bbase + 16*512 + k);
    frag8 b2 = *(const frag8*)(bbase + 32*512 + k);
    frag8 b3 = *(const frag8*)(bbase + 48*512 + k);
    acc0 = __builtin_amdgcn_mfma_f32_16x16x32_bf16(a, b0, acc0, 0, 0, 0);
    acc1 = __builtin_amdgcn_mfma_f32_16x16x32_bf16(a, b1, acc1, 0, 0, 0);
    acc2 = __builtin_amdgcn_mfma_f32_16x16x32_bf16(a, b2, acc2, 0, 0, 0);
    acc3 = __builtin_amdgcn_mfma_f32_16x16x32_bf16(a, b3, acc3, 0, 0, 0);
  }
  int rowb = mt*16 + (lane >> 4)*4;
  int col  = nt*64 + (lane & 15);
  #pragma unroll
  for (int i=0;i<4;i++){
    P16[(size_t)(rowb+i)*256 + col     ] = f2bf(acc0[i]);
    P16[(size_t)(rowb+i)*256 + col + 16] = f2bf(acc1[i]);
    P16[(size_t)(rowb+i)*256 + col + 32] = f2bf(acc2[i]);
    P16[(size_t)(rowb+i)*256 + col + 48] = f2bf(acc3[i]);
  }
}

// per-edge MLP head: 16 lanes/edge, bf16 P loads
__global__ void k_edge(const int* __restrict__ ei, const unsigned short* __restrict__ P16,
                       const float* __restrict__ b1,
                       const float* __restrict__ w2, const float* __restrict__ b2,
                       float* __restrict__ out){
  int e = blockIdx.x*16 + (threadIdx.x >> 4);
  int l = threadIdx.x & 15;            // lane covers channels [l*8, l*8+8)
  if (e >= EE) return;
  int s = ei[e], d = ei[EE+e];
  const u16x8 Av = *(const u16x8*)&P16[(size_t)s*256 + l*8];
  const u16x8 Bv = *(const u16x8*)&P16[(size_t)d*256 + 128 + l*8];
  const float4 b1a = *(const float4*)&b1[l*8];
  const float4 b1b = *(const float4*)&b1[l*8+4];
  const float4 w2a = *(const float4*)&w2[l*8];
  const float4 w2b = *(const float4*)&w2[l*8+4];
  float h0 = fmaxf(bf2f(Av[0])+bf2f(Bv[0])+b1a.x, 0.f);
  float h1 = fmaxf(bf2f(Av[1])+bf2f(Bv[1])+b1a.y, 0.f);
  float h2 = fmaxf(bf2f(Av[2])+bf2f(Bv[2])+b1a.z, 0.f);
  float h3 = fmaxf(bf2f(Av[3])+bf2f(Bv[3])+b1a.w, 0.f);
  float h4 = fmaxf(bf2f(Av[4])+bf2f(Bv[4])+b1b.x, 0.f);
  float h5 = fmaxf(bf2f(Av[5])+bf2f(Bv[5])+b1b.y, 0.f);
  float h6 = fmaxf(bf2f(Av[6])+bf2f(Bv[6])+b1b.z, 0.f);
  float h7 = fmaxf(bf2f(Av[7])+bf2f(Bv[7])+b1b.w, 0.f);
  float acc = h0*w2a.x + h1*w2a.y + h2*w2a.z + h3*w2a.w
            + h4*w2b.x + h5*w2b.y + h6*w2b.z + h7*w2b.w;
  #pragma unroll
  for (int m=8;m>0;m>>=1) acc += __shfl_xor(acc,m,64);
  if (l==0) out[e] = 1.f/(1.f + expf(-(acc + b2[0])));
}

extern "C" void kernel_launch(void* const* d_in, const int* in_sizes, int n_in,
                              void* d_out, int out_size, void* d_ws, size_t ws_size,
                              hipStream_t stream){
  const float* basis0 = (const float*)d_in[0];
  const float* comp0  = (const float*)d_in[1];
  const float* root0  = (const float*)d_in[2];
  const float* rbias0 = (const float*)d_in[3];
  const float* basis1 = (const float*)d_in[4];
  const float* comp1  = (const float*)d_in[5];
  const float* root1  = (const float*)d_in[6];
  const float* rbias1 = (const float*)d_in[7];
  const float* basis2 = (const float*)d_in[8];
  const float* comp2  = (const float*)d_in[9];
  const float* root2  = (const float*)d_in[10];
  const float* rbias2 = (const float*)d_in[11];
  const float* basis3 = (const float*)d_in[12];
  const float* comp3  = (const float*)d_in[13];
  const float* root3  = (const float*)d_in[14];
  const float* rbias3 = (const float*)d_in[15];
  const float* gat_w = (const float*)d_in[16];
  const float* a_src = (const float*)d_in[17];
  const float* a_dst = (const float*)d_in[18];
  const float* gat_b = (const float*)d_in[19];
  const float* w1 = (const float*)d_in[20];
  const float* b1 = (const float*)d_in[21];
  const float* w2 = (const float*)d_in[22];
  const float* b2 = (const float*)d_in[23];
  const int* ei = (const int*)d_in[24];
  const int* et = (const int*)d_in[25];
  float* out = (float*)d_out;

  // workspace carve-up (16B-aligned sections)
  float* p = (float*)d_ws;
  int* cursor = (int*)p; p += NN;              // doubles as degree after k_pdc
  int* pks    = (int*)p; p += NN*CAP;          // bucket CSR (64 slots/node)
  unsigned short* W016 = (unsigned short*)p; p += NN*32;       // 2*NN*32 bf16
  float* Wcat = p; p += 24576;
  unsigned short* Bt16 = (unsigned short*)p; p += 256*512/2;
  unsigned short* H16a = (unsigned short*)p; p += NN*96;       // NN*192 bf16
  unsigned short* H16b = (unsigned short*)p; p += NN*96;       // NN*192 bf16
  unsigned short* h16  = (unsigned short*)p; p += NN*256;      // NN*512 bf16
  float* asv  = p; p += NN;
  float* adv  = p; p += NN;
  unsigned short* gout16 = (unsigned short*)p; p += NN*256;    // NN*512 bf16
  unsigned short* P16 = (unsigned short*)p; p += NN*128;       // NN*256 bf16

  auto grid = [](long long n){ return dim3((unsigned)((n + 255)/256)); };

  // ---- zero cursor only, then single fused prep kernel ----
  hipMemsetAsync(cursor, 0, (size_t)NN*sizeof(int), stream);
  k_pdc<<<grid(2LL*NN*32 + 24576 + 256*512),256,0,stream>>>(ei, et, cursor, pks,
        basis0, comp0, basis1,comp1,root1, basis2,comp2,root2,
        basis3,comp3,root3, w1, W016, Wcat, Bt16);

  // ---- RGCN stack (fused gather+mm per layer; rel-counts derived locally) ----
  k_f1<<<dim3(NN/8),256,0,stream>>>(W016, root0, rbias0, cursor, pks, Wcat, H16a);
  k_f2<<<dim3(NN/8),256,0,stream>>>(H16a, rbias1, cursor, pks, Wcat + 6144, H16b);
  k_f3<<<dim3(NN/8),256,0,stream>>>(H16b, rbias2, cursor, pks, Wcat + 18432, H16a);
  k_f4<<<dim3(NN/8),256,0,stream>>>(H16a, rbias3, cursor, pks,
                                    gat_w, a_src, a_dst, h16, asv, adv);

  // ---- GAT softmax+aggregate (1 wave/node) ----
  k_gsa<<<dim3(NN),64,0,stream>>>(cursor, pks, asv, adv, h16, gat_b, gout16);

  // ---- edge MLP: MFMA GEMM then per-edge head ----
  k_AB<<<dim3(1500),64,0,stream>>>(gout16, Bt16, P16);
  k_edge<<<dim3((EE+15)/16),256,0,stream>>>(ei, P16, b1, w2, b2, out);
}